// Round 13
// baseline (9264.555 us; speedup 1.0000x reference)
//
#include <hip/hip_runtime.h>
#include <hip/hip_fp16.h>

#define BB 128
#define II 64
#define SS 2048
#define HH 128
#define GG 512   // 4*H
#define OO 64
#define TT 32    // x time-tile width (fallback kernel)
#define TCH 128  // precompute t-chunk
#define XPBYTES ((size_t)BB * SS * GG * 2)

typedef _Float16 f16x2 __attribute__((ext_vector_type(2)));
union F4H { float4 f4; f16x2 h[4]; };

__device__ __forceinline__ f16x2 pack2(float a, float b) {
    f16x2 r; r.x = (_Float16)a; r.y = (_Float16)b; return r;
}

__device__ __forceinline__ float dot2(f16x2 w, f16x2 v, float c) {
#if __has_builtin(__builtin_amdgcn_fdot2)
    return __builtin_amdgcn_fdot2(w, v, c, false);
#else
    return fmaf((float)w.x, (float)v.x, fmaf((float)w.y, (float)v.y, c));
#endif
}

__device__ __forceinline__ float sigm(float v) {
    return __builtin_amdgcn_rcpf(1.0f + __expf(-v));
}
// original tanh (fallback kernel keeps R1 bit-exact behavior)
__device__ __forceinline__ float tanh_f(float v) {
    float a = fabsf(v);
    float e = __expf(-2.0f * a);
    float r = (1.0f - e) * __builtin_amdgcn_rcpf(1.0f + e);
    return v < 0.0f ? -r : r;
}
// branch-free tanh = 2*sigm(2v)-1 (safe at +/-inf)
__device__ __forceinline__ float tanh_c(float v) {
    return fmaf(2.0f, __builtin_amdgcn_rcpf(1.0f + __expf(-2.0f * v)), -1.0f);
}

// quad-scope shuffle via DPP quad_perm (VALU pipe ~4cyc)
template <int CTRL>
__device__ __forceinline__ float qdpp(float x) {
    return __int_as_float(__builtin_amdgcn_update_dpp(
        0, __float_as_int(x), CTRL, 0xF, 0xF, true));
}
#define QP_XOR3 0x1B   // [3,2,1,0]
#define QP_BC0  0x00   // [0,0,0,0]
#define QP_BC1  0x55   // [1,1,1,1]
#define QP_BC2  0xAA   // [2,2,2,2]

// ============================================================================
// XP precompute: XP[b][t][j] = sum_i x[b,i,t] * Wx_out[i,j], stored f16.
// ============================================================================
__global__ void __launch_bounds__(512)
xp_gemm(const float* __restrict__ x, const float* __restrict__ Wx_out,
        _Float16* __restrict__ xp)
{
    const int tc = blockIdx.x;          // 0..15
    const int b  = blockIdx.y;          // 0..127
    const int j  = threadIdx.x;         // gate column 0..511
    const int t0 = tc * TCH;

    __shared__ __align__(16) f16x2 x2s[TCH][36];

    f16x2 w2[32];
#pragma unroll
    for (int c = 0; c < 32; ++c)
        w2[c] = pack2(Wx_out[(2 * c) * GG + j], Wx_out[(2 * c + 1) * GG + j]);

    const float* xrow = x + (size_t)b * II * SS;
    const int r = j >> 3;
#pragma unroll
    for (int rep = 0; rep < 4; ++rep) {
        const int u = (j & 7) + 8 * rep;
        const float4 v = *(const float4*)(xrow + (size_t)r * SS + t0 + 4 * u);
        const int c = r >> 1, half = r & 1;
        ((_Float16*)&x2s[4 * u + 0][c])[half] = (_Float16)v.x;
        ((_Float16*)&x2s[4 * u + 1][c])[half] = (_Float16)v.y;
        ((_Float16*)&x2s[4 * u + 2][c])[half] = (_Float16)v.z;
        ((_Float16*)&x2s[4 * u + 3][c])[half] = (_Float16)v.w;
    }
    __syncthreads();

    _Float16* xpo = xp + ((size_t)b * SS + t0) * GG + j;
#pragma unroll 4
    for (int tt = 0; tt < TCH; ++tt) {
        const float4* xr4 = (const float4*)&x2s[tt][0];
        float a0 = 0.f, a1 = 0.f;
#pragma unroll
        for (int q = 0; q < 8; ++q) {
            F4H u; u.f4 = xr4[q];
            a0 = dot2(w2[4 * q + 0], u.h[0], a0);
            a1 = dot2(w2[4 * q + 1], u.h[1], a1);
            a0 = dot2(w2[4 * q + 2], u.h[2], a0);
            a1 = dot2(w2[4 * q + 3], u.h[3], a1);
        }
        xpo[(size_t)tt * GG] = (_Float16)(a0 + a1);
    }
}

// ============================================================================
// Scan — R9/R12 base (3520-3526 us) with ONE isolated change: projection
// E(t-1) moved from the post-S2 serial slot into PHASE A's window of step t.
// Raceless WITHOUT double-buffering: between S2(t-1) and C-tail(t), hb
// stably holds h(t-1) — exactly what A(t)'s dots read — and no thread
// writes hb in that interval (C-tail's hb[m] write is after S1). So E's
// independent dot/shuffle chain fills A's dot-loop issue shadow instead of
// sitting serially between S2 and the loop branch.
// Contrast with R8/R11 (both spilled): those put E in phase C's window,
// which REQUIRES dbuf-hb + temps live across the 160-inst C region. Here
// E's ~5 temps are live only inside the low-pressure A region.
// REGISTER CLIFF (measured R8+R11): any extra value live across phase C
// spills -> FETCH 173->800+ MB -> 6x. Watchdog: FETCH must stay ~173 MB.
// ============================================================================
__global__ void __launch_bounds__(512)
nlstm_scan_xp(
    const _Float16* __restrict__ xp,
    const float* __restrict__ Wh_out, const float* __restrict__ b_out,
    const float* __restrict__ Wx_in, const float* __restrict__ Wh_in,
    const float* __restrict__ b_in,
    const float* __restrict__ W_lin, const float* __restrict__ b_lin,
    float* __restrict__ out)
{
    const int b = blockIdx.x;
    const int j = threadIdx.x;
    const int g = j & 3;          // gate lane within quad: 0=i 1=f 2=o 3=g
    const int m = j >> 2;         // h-column 0..127
    const int col = g * 128 + m;  // gate column in canonical layout

    __shared__ __align__(16) float4 wlf[16 * 66];      // W_lin fp16, 16.5 KB
    __shared__ __align__(16) _Float16 hb[HH];          // h fp16
    __shared__ __align__(16) _Float16 xib[HH];         // x_in fp16
    __shared__ __align__(16) _Float16 hib[HH];         // h_in fp16

    // register-resident fp16 weights (column col) : 192 regs (overflow->AGPR,
    // measured free on gfx950 unified file — R10)
    f16x2 who[HH / 2], wxi[HH / 2], whi[HH / 2];
#pragma unroll
    for (int q = 0; q < HH / 2; ++q)
        who[q] = pack2(Wh_out[(2 * q) * GG + col], Wh_out[(2 * q + 1) * GG + col]);
#pragma unroll
    for (int q = 0; q < HH / 2; ++q)
        wxi[q] = pack2(Wx_in[(2 * q) * GG + col], Wx_in[(2 * q + 1) * GG + col]);
#pragma unroll
    for (int q = 0; q < HH / 2; ++q)
        whi[q] = pack2(Wh_in[(2 * q) * GG + col], Wh_in[(2 * q + 1) * GG + col]);

    const float bo = b_out[col];
    const float bi = b_in[col];
    // branch-free activation: g<3 -> sigm(x); g==3 -> tanh(x)=2*sigm(2x)-1
    const float kk = (g == 3) ? 2.0f : 1.0f;
    const float aa = (g == 3) ? 2.0f : 1.0f;
    const float cc = (g == 3) ? -1.0f : 0.0f;

    const int   pn = j >> 3;
    const int   ps = j & 7;
    const float bl = b_lin[pn];

    // W_lin -> LDS fp16 (1024 chunks, 2 per thread)
#pragma unroll
    for (int r = 0; r < 2; ++r) {
        const int mm = r * 512 + j;
        const int c = mm >> 6, n = mm & 63;
        F4H u;
#pragma unroll
        for (int q = 0; q < 4; ++q)
            u.h[q] = pack2(W_lin[n * HH + 8 * c + 2 * q],
                           W_lin[n * HH + 8 * c + 2 * q + 1]);
        wlf[c * 66 + n] = u.f4;
    }

    if (j < HH) { hb[j] = (_Float16)0.f; xib[j] = (_Float16)0.f; hib[j] = (_Float16)0.f; }
    float c_reg = 0.f, cn_reg = 0.f;   // redundant in all 4 quad lanes
    float o_all = 0.f;                 // outer o, broadcast each step
    __syncthreads();

    const _Float16* xpr = xp + (size_t)b * SS * GG + col;
    float* orow = out + (size_t)b * SS * OO;
    const float4* hb4 = (const float4*)hb;   // 16 chunks
    const float4* xi4 = (const float4*)xib;  // 16 chunks
    const float4* hi4 = (const float4*)hib;  // 16 chunks

    _Float16 xpc = xpr[0];

#pragma unroll 1
    for (int t = 0; t < SS; ++t) {
        // ---- phase A: outer gate for col = XP + h@Wh_out + b ----
        // (reads hb = h(t-1), stable since S2 of step t-1)
        float a0 = bo + (float)xpc, a1 = 0.f, a2 = 0.f, a3 = 0.f;
#pragma unroll
        for (int c = 0; c < 16; ++c) {
            F4H hu; hu.f4 = hb4[c];
            a0 = dot2(who[4 * c + 0], hu.h[0], a0);
            a1 = dot2(who[4 * c + 1], hu.h[1], a1);
            a2 = dot2(who[4 * c + 2], hu.h[2], a2);
            a3 = dot2(who[4 * c + 3], hu.h[3], a3);
        }
        // prefetch next step's XP (independent; lands during phase C)
        const _Float16 xpn = xpr[(size_t)((t + 1) & (SS - 1)) * GG];

        // ---- projection E(t-1): fills A's dot-chain shadow ----
        // reads hb = h(t-1); no writer of hb exists until C-tail (post-S1)
        if (t > 0) {
            float p = 0.f;
#pragma unroll
            for (int q = 0; q < 2; ++q) {
                const int c = 2 * ps + q;
                F4H hu; hu.f4 = hb4[c];
                F4H wu; wu.f4 = wlf[c * 66 + pn];
                p = dot2(wu.h[0], hu.h[0], p);
                p = dot2(wu.h[1], hu.h[1], p);
                p = dot2(wu.h[2], hu.h[2], p);
                p = dot2(wu.h[3], hu.h[3], p);
            }
            p += __shfl_down(p, 4, 8);
            p += __shfl_down(p, 2, 8);
            p += __shfl_down(p, 1, 8);
            if (ps == 0) orow[(size_t)(t - 1) * OO + pn] = p + bl;
        }

        // ---- phase A tail ----
        const float accA = (a0 + a1) + (a2 + a3);
        const float v = fmaf(aa, sigm(kk * accA), cc);   // i/f/o/g by lane
        // quad tail (DPP): x_in = i*g at lane0, h_in = f*c at lane1
        const float vg3 = qdpp<QP_XOR3>(v);   // lane0 <- g-value
        o_all = qdpp<QP_BC2>(v);              // everyone keeps outer o
        if (g == 0)      xib[m] = (_Float16)(v * vg3);
        else if (g == 1) hib[m] = (_Float16)(v * c_reg);  // c_reg redundant-valid
        __syncthreads();   // S1

        // ---- phase C: inner gate for col ----
        float c0 = bi, c1 = 0.f, c2 = 0.f, c3 = 0.f;
#pragma unroll
        for (int c = 0; c < 16; ++c) {
            F4H xu; xu.f4 = xi4[c];
            c0 = dot2(wxi[4 * c + 0], xu.h[0], c0);
            c1 = dot2(wxi[4 * c + 1], xu.h[1], c1);
            c2 = dot2(wxi[4 * c + 2], xu.h[2], c2);
            c3 = dot2(wxi[4 * c + 3], xu.h[3], c3);
        }
#pragma unroll
        for (int c = 0; c < 16; ++c) {
            F4H hu; hu.f4 = hi4[c];
            c0 = dot2(whi[4 * c + 0], hu.h[0], c0);
            c1 = dot2(whi[4 * c + 1], hu.h[1], c1);
            c2 = dot2(whi[4 * c + 2], hu.h[2], c2);
            c3 = dot2(whi[4 * c + 3], hu.h[3], c3);
        }
        const float accC = (c0 + c1) + (c2 + c3);
        const float u = fmaf(aa, sigm(kk * accC), cc);    // ii/fi/oi/gi by lane
        // quad tail (DPP, redundant update in all lanes; P/F/O independent):
        const float ug3 = qdpp<QP_XOR3>(u);
        const float p0  = u * ug3;                 // ii*gi valid at lanes 0,3
        const float P   = qdpp<QP_BC0>(p0);        // ii*gi everywhere
        const float F   = qdpp<QP_BC1>(u);         // fi everywhere
        const float O   = qdpp<QP_BC2>(u);         // oi everywhere
        const float cn_new = fmaf(F, cn_reg, P);
        cn_reg = cn_new;
        const float c_new = O * tanh_c(cn_new);
        c_reg = c_new;
        const float h_new = o_all * tanh_c(c_new);
        if (g == 2) hb[m] = (_Float16)h_new;
        xpc = xpn;
        __syncthreads();   // S2
    }

    // ---- epilogue: projection for t = SS-1 (hb = h(SS-1)) ----
    {
        float p = 0.f;
#pragma unroll
        for (int q = 0; q < 2; ++q) {
            const int c = 2 * ps + q;
            F4H hu; hu.f4 = hb4[c];
            F4H wu; wu.f4 = wlf[c * 66 + pn];
            p = dot2(wu.h[0], hu.h[0], p);
            p = dot2(wu.h[1], hu.h[1], p);
            p = dot2(wu.h[2], hu.h[2], p);
            p = dot2(wu.h[3], hu.h[3], p);
        }
        p += __shfl_down(p, 4, 8);
        p += __shfl_down(p, 2, 8);
        p += __shfl_down(p, 1, 8);
        if (ps == 0) orow[(size_t)(SS - 1) * OO + pn] = p + bl;
    }
}

// ============================================================================
// FALLBACK: exact R1 kernel (measured 4364 us) for when ws is too small.
// ============================================================================
__global__ void
__attribute__((amdgpu_flat_work_group_size(512, 512)))
__attribute__((amdgpu_waves_per_eu(2, 2)))
nlstm_scan(
    const float* __restrict__ x,
    const float* __restrict__ Wx_out, const float* __restrict__ Wh_out,
    const float* __restrict__ b_out,
    const float* __restrict__ Wx_in, const float* __restrict__ Wh_in,
    const float* __restrict__ b_in,
    const float* __restrict__ W_lin, const float* __restrict__ b_lin,
    float* __restrict__ out)
{
    const int b = blockIdx.x;
    const int j = threadIdx.x;

    __shared__ __align__(16) float4 wxf[8 * 512];
    __shared__ __align__(16) float4 wlf[16 * 66];
    __shared__ float xt[2][II][TT + 1];
    __shared__ __align__(16) f16x2 xb[2][II / 2];
    __shared__ __align__(16) f16x2 hb[HH / 2];
    __shared__ __align__(16) f16x2 xib[HH / 2];
    __shared__ __align__(16) f16x2 hib[HH / 2];
    __shared__ float cb[HH];
    __shared__ float cnb[HH];
    __shared__ float actO[GG];
    __shared__ float actI[GG];

    f16x2 who[HH / 2], wxi[HH / 2], whi[HH / 2];
#pragma unroll
    for (int m = 0; m < HH / 2; ++m)
        who[m] = pack2(Wh_out[(2 * m) * GG + j], Wh_out[(2 * m + 1) * GG + j]);
#pragma unroll
    for (int m = 0; m < HH / 2; ++m)
        wxi[m] = pack2(Wx_in[(2 * m) * GG + j], Wx_in[(2 * m + 1) * GG + j]);
#pragma unroll
    for (int m = 0; m < HH / 2; ++m)
        whi[m] = pack2(Wh_in[(2 * m) * GG + j], Wh_in[(2 * m + 1) * GG + j]);

    const float bo = b_out[j];
    const float bi = b_in[j];
    const int   pn = j >> 3;
    const int   ps = j & 7;
    const float bl = b_lin[pn];

#pragma unroll
    for (int c = 0; c < 8; ++c) {
        F4H u;
#pragma unroll
        for (int q = 0; q < 4; ++q)
            u.h[q] = pack2(Wx_out[(8 * c + 2 * q) * GG + j],
                           Wx_out[(8 * c + 2 * q + 1) * GG + j]);
        wxf[c * 512 + j] = u.f4;
    }
#pragma unroll
    for (int r = 0; r < 2; ++r) {
        const int m = r * 512 + j;
        const int c = m >> 6, n = m & 63;
        F4H u;
#pragma unroll
        for (int q = 0; q < 4; ++q)
            u.h[q] = pack2(W_lin[n * HH + 8 * c + 2 * q],
                           W_lin[n * HH + 8 * c + 2 * q + 1]);
        wlf[c * 66 + n] = u.f4;
    }

    const float* xrow = x + (size_t)b * II * SS;
    float* orow = out + (size_t)b * SS * OO;

    {
        const int row = j >> 3, tc = j & 7;
        const float4 v = *(const float4*)(xrow + (size_t)row * SS + 4 * tc);
        float* dst = &xt[0][row][4 * tc];
        dst[0] = v.x; dst[1] = v.y; dst[2] = v.z; dst[3] = v.w;
    }
    if (j < HH / 2) hb[j] = pack2(0.f, 0.f);
    if (j < HH) { cb[j] = 0.f; cnb[j] = 0.f; }
    if (j >= 256 && j < 256 + 32) {
        const int m = j - 256;
        xb[0][m] = pack2(xrow[(2 * m) * SS], xrow[(2 * m + 1) * SS]);
    }
    __syncthreads();

    const float4* hb4 = (const float4*)hb;
    const float4* xi4 = (const float4*)xib;
    const float4* hi4 = (const float4*)hib;

#pragma unroll 1
    for (int t = 0; t < SS; ++t) {
        const float4* xcur = (const float4*)xb[t & 1];
        float a0 = bo, a1 = 0.f, a2 = 0.f, a3 = 0.f;
#pragma unroll
        for (int c = 0; c < 8; ++c) {
            F4H xu; xu.f4 = xcur[c];
            F4H wu; wu.f4 = wxf[c * 512 + j];
            a0 = dot2(wu.h[0], xu.h[0], a0);
            a1 = dot2(wu.h[1], xu.h[1], a1);
            a2 = dot2(wu.h[2], xu.h[2], a2);
            a3 = dot2(wu.h[3], xu.h[3], a3);
        }
#pragma unroll
        for (int c = 0; c < 16; ++c) {
            F4H hu; hu.f4 = hb4[c];
            a0 = dot2(who[4 * c + 0], hu.h[0], a0);
            a1 = dot2(who[4 * c + 1], hu.h[1], a1);
            a2 = dot2(who[4 * c + 2], hu.h[2], a2);
            a3 = dot2(who[4 * c + 3], hu.h[3], a3);
        }
        {
            const float acc = (a0 + a1) + (a2 + a3);
            actO[j] = (j < 384) ? sigm(acc) : tanh_f(acc);
        }
        __syncthreads();

        if (j < II) {
            xib[j] = pack2(actO[2 * j] * actO[384 + 2 * j],
                           actO[2 * j + 1] * actO[384 + 2 * j + 1]);
        } else if (j < II + HH / 2) {
            const int m = j - II;
            hib[m] = pack2(actO[HH + 2 * m] * cb[2 * m],
                           actO[HH + 2 * m + 1] * cb[2 * m + 1]);
        }
        __syncthreads();

        float c0 = bi, c1 = 0.f, c2 = 0.f, c3 = 0.f;
#pragma unroll
        for (int c = 0; c < 16; ++c) {
            F4H xu; xu.f4 = xi4[c];
            c0 = dot2(wxi[4 * c + 0], xu.h[0], c0);
            c1 = dot2(wxi[4 * c + 1], xu.h[1], c1);
            c2 = dot2(wxi[4 * c + 2], xu.h[2], c2);
            c3 = dot2(wxi[4 * c + 3], xu.h[3], c3);
        }
#pragma unroll
        for (int c = 0; c < 16; ++c) {
            F4H hu; hu.f4 = hi4[c];
            c0 = dot2(whi[4 * c + 0], hu.h[0], c0);
            c1 = dot2(whi[4 * c + 1], hu.h[1], c1);
            c2 = dot2(whi[4 * c + 2], hu.h[2], c2);
            c3 = dot2(whi[4 * c + 3], hu.h[3], c3);
        }
        {
            const float acc2 = (c0 + c1) + (c2 + c3);
            actI[j] = (j < 384) ? sigm(acc2) : tanh_f(acc2);
        }
        __syncthreads();

        const bool doTile = ((t & 31) == 30) && (t + 2 < SS);
        float4 xld; int Tn = 0;
        if (doTile) {
            Tn = (t + 2) >> 5;
            const int row = j >> 3, tc = j & 7;
            xld = *(const float4*)(xrow + (size_t)row * SS + TT * Tn + 4 * tc);
        }
        if (j < HH) {
            const float cn_new = actI[HH + j] * cnb[j] + actI[j] * actI[384 + j];
            const float c_new  = actI[2 * HH + j] * tanh_f(cn_new);
            const float h_new  = actO[2 * HH + j] * tanh_f(c_new);
            cnb[j] = cn_new;
            cb[j]  = c_new;
            ((_Float16*)hb)[j] = (_Float16)h_new;
        } else if (j < HH + 32) {
            const int m = j - HH;
            const int tn = t + 1;
            const int tbn = (tn >> 5) & 1, ttn = tn & 31;
            xb[tn & 1][m] = pack2(xt[tbn][2 * m][ttn],
                                  xt[tbn][2 * m + 1][ttn]);
        }
        if (doTile) {
            const int row = j >> 3, tc = j & 7;
            float* dst = &xt[Tn & 1][row][4 * tc];
            dst[0] = xld.x; dst[1] = xld.y; dst[2] = xld.z; dst[3] = xld.w;
        }
        __syncthreads();

        float p = 0.f;
#pragma unroll
        for (int q = 0; q < 2; ++q) {
            const int c = 2 * ps + q;
            F4H hu; hu.f4 = hb4[c];
            F4H wu; wu.f4 = wlf[c * 66 + pn];
            p = dot2(wu.h[0], hu.h[0], p);
            p = dot2(wu.h[1], hu.h[1], p);
            p = dot2(wu.h[2], hu.h[2], p);
            p = dot2(wu.h[3], hu.h[3], p);
        }
        p += __shfl_down(p, 4, 8);
        p += __shfl_down(p, 2, 8);
        p += __shfl_down(p, 1, 8);
        if (ps == 0) orow[t * OO + pn] = p + bl;
    }
}

extern "C" void kernel_launch(void* const* d_in, const int* in_sizes, int n_in,
                              void* d_out, int out_size, void* d_ws, size_t ws_size,
                              hipStream_t stream) {
    (void)in_sizes; (void)n_in; (void)out_size;
    const float* x      = (const float*)d_in[0];
    const float* Wx_out = (const float*)d_in[1];
    const float* Wh_out = (const float*)d_in[2];
    const float* b_out  = (const float*)d_in[3];
    const float* Wx_in  = (const float*)d_in[4];
    const float* Wh_in  = (const float*)d_in[5];
    const float* b_in   = (const float*)d_in[6];
    const float* W_lin  = (const float*)d_in[7];
    const float* b_lin  = (const float*)d_in[8];
    float* out = (float*)d_out;

    if (d_ws != nullptr && ws_size >= XPBYTES) {
        _Float16* xpw = (_Float16*)d_ws;
        xp_gemm<<<dim3(16, BB), dim3(512), 0, stream>>>(x, Wx_out, xpw);
        nlstm_scan_xp<<<dim3(BB), dim3(512), 0, stream>>>(
            xpw, Wh_out, b_out, Wx_in, Wh_in, b_in, W_lin, b_lin, out);
    } else {
        nlstm_scan<<<dim3(BB), dim3(512), 0, stream>>>(
            x, Wx_out, Wh_out, b_out, Wx_in, Wh_in, b_in, W_lin, b_lin, out);
    }
}

// Round 14
// 3531.610 us; speedup vs baseline: 2.6233x; 2.6233x over previous
//
#include <hip/hip_runtime.h>
#include <hip/hip_fp16.h>

#define BB 128
#define II 64
#define SS 2048
#define HH 128
#define GG 512   // 4*H
#define OO 64
#define TT 32    // x time-tile width (fallback kernel)
#define TCH 128  // precompute t-chunk
#define XPBYTES ((size_t)BB * SS * GG * 2)

typedef _Float16 f16x2 __attribute__((ext_vector_type(2)));
union F4H { float4 f4; f16x2 h[4]; };

__device__ __forceinline__ f16x2 pack2(float a, float b) {
    f16x2 r; r.x = (_Float16)a; r.y = (_Float16)b; return r;
}

__device__ __forceinline__ float dot2(f16x2 w, f16x2 v, float c) {
#if __has_builtin(__builtin_amdgcn_fdot2)
    return __builtin_amdgcn_fdot2(w, v, c, false);
#else
    return fmaf((float)w.x, (float)v.x, fmaf((float)w.y, (float)v.y, c));
#endif
}

__device__ __forceinline__ float sigm(float v) {
    return __builtin_amdgcn_rcpf(1.0f + __expf(-v));
}
// original tanh (fallback kernel keeps R1 bit-exact behavior)
__device__ __forceinline__ float tanh_f(float v) {
    float a = fabsf(v);
    float e = __expf(-2.0f * a);
    float r = (1.0f - e) * __builtin_amdgcn_rcpf(1.0f + e);
    return v < 0.0f ? -r : r;
}
// branch-free tanh = 2*sigm(2v)-1 (safe at +/-inf)
__device__ __forceinline__ float tanh_c(float v) {
    return fmaf(2.0f, __builtin_amdgcn_rcpf(1.0f + __expf(-2.0f * v)), -1.0f);
}

// quad-scope shuffle via DPP quad_perm (VALU pipe ~4cyc)
template <int CTRL>
__device__ __forceinline__ float qdpp(float x) {
    return __int_as_float(__builtin_amdgcn_update_dpp(
        0, __float_as_int(x), CTRL, 0xF, 0xF, true));
}
#define QP_XOR3 0x1B   // [3,2,1,0]
#define QP_BC0  0x00   // [0,0,0,0]
#define QP_BC1  0x55   // [1,1,1,1]
#define QP_BC2  0xAA   // [2,2,2,2]

// ============================================================================
// XP precompute: XP[b][t][j] = sum_i x[b,i,t] * Wx_out[i,j], stored f16.
// ============================================================================
__global__ void __launch_bounds__(512)
xp_gemm(const float* __restrict__ x, const float* __restrict__ Wx_out,
        _Float16* __restrict__ xp)
{
    const int tc = blockIdx.x;          // 0..15
    const int b  = blockIdx.y;          // 0..127
    const int j  = threadIdx.x;         // gate column 0..511
    const int t0 = tc * TCH;

    __shared__ __align__(16) f16x2 x2s[TCH][36];

    f16x2 w2[32];
#pragma unroll
    for (int c = 0; c < 32; ++c)
        w2[c] = pack2(Wx_out[(2 * c) * GG + j], Wx_out[(2 * c + 1) * GG + j]);

    const float* xrow = x + (size_t)b * II * SS;
    const int r = j >> 3;
#pragma unroll
    for (int rep = 0; rep < 4; ++rep) {
        const int u = (j & 7) + 8 * rep;
        const float4 v = *(const float4*)(xrow + (size_t)r * SS + t0 + 4 * u);
        const int c = r >> 1, half = r & 1;
        ((_Float16*)&x2s[4 * u + 0][c])[half] = (_Float16)v.x;
        ((_Float16*)&x2s[4 * u + 1][c])[half] = (_Float16)v.y;
        ((_Float16*)&x2s[4 * u + 2][c])[half] = (_Float16)v.z;
        ((_Float16*)&x2s[4 * u + 3][c])[half] = (_Float16)v.w;
    }
    __syncthreads();

    _Float16* xpo = xp + ((size_t)b * SS + t0) * GG + j;
#pragma unroll 4
    for (int tt = 0; tt < TCH; ++tt) {
        const float4* xr4 = (const float4*)&x2s[tt][0];
        float a0 = 0.f, a1 = 0.f;
#pragma unroll
        for (int q = 0; q < 8; ++q) {
            F4H u; u.f4 = xr4[q];
            a0 = dot2(w2[4 * q + 0], u.h[0], a0);
            a1 = dot2(w2[4 * q + 1], u.h[1], a1);
            a0 = dot2(w2[4 * q + 2], u.h[2], a0);
            a1 = dot2(w2[4 * q + 3], u.h[3], a1);
        }
        xpo[(size_t)tt * GG] = (_Float16)(a0 + a1);
    }
}

// ============================================================================
// Scan — FINAL (verified optimum, measured 3520-3526 us in R9/R12).
// Quad-gate layout: thread j owns gate g=j&3 of h-column m=j>>2
// (col = g*128+m); a lane-quad holds (i,f,o,g) of one column.
//   - elementwise phases are quad-local: DPP quad_perm + register math
//   - c/cn redundant in all 4 lanes -> update broadcasts independent
//   - 2 barriers/step (minimum: S1 protects A-tail->C, S2 protects C-tail->A)
//   - XP (input GEMM) hoisted to xp_gemm; phase A's x-part is 1 f16 load
//     prefetched a full step ahead
// DO-NOT-TOUCH notes (all measured):
//   * REGISTER CLIFF (R8,R11): 192 weight regs on the 128-arch-VGPR budget
//     leaves ~0 allocator margin. Extra values live across the 128-dot2
//     phase C spill -> FETCH 173->800+ MB -> 6x regression.
//   * E PLACEMENT (R13): projection E must stay post-S2. Moving it into
//     phase A's window (store+shuffles just before S1's vmcnt drain)
//     caused +6600 stall cyc/step (2.6x) with NO spill.
//   * LDS-resident Wh_out is 4% slower (R10). MFMA restructure serializes
//     pipes (R5). Cross-block split pays HBM RTT (R3).
// ============================================================================
__global__ void __launch_bounds__(512)
nlstm_scan_xp(
    const _Float16* __restrict__ xp,
    const float* __restrict__ Wh_out, const float* __restrict__ b_out,
    const float* __restrict__ Wx_in, const float* __restrict__ Wh_in,
    const float* __restrict__ b_in,
    const float* __restrict__ W_lin, const float* __restrict__ b_lin,
    float* __restrict__ out)
{
    const int b = blockIdx.x;
    const int j = threadIdx.x;
    const int g = j & 3;          // gate lane within quad: 0=i 1=f 2=o 3=g
    const int m = j >> 2;         // h-column 0..127
    const int col = g * 128 + m;  // gate column in canonical layout

    __shared__ __align__(16) float4 wlf[16 * 66];      // W_lin fp16, 16.5 KB
    __shared__ __align__(16) _Float16 hb[HH];          // h fp16
    __shared__ __align__(16) _Float16 xib[HH];         // x_in fp16
    __shared__ __align__(16) _Float16 hib[HH];         // h_in fp16

    // register-resident fp16 weights (column col) : 192 regs (overflow->AGPR,
    // measured free on gfx950 unified file — R10)
    f16x2 who[HH / 2], wxi[HH / 2], whi[HH / 2];
#pragma unroll
    for (int q = 0; q < HH / 2; ++q)
        who[q] = pack2(Wh_out[(2 * q) * GG + col], Wh_out[(2 * q + 1) * GG + col]);
#pragma unroll
    for (int q = 0; q < HH / 2; ++q)
        wxi[q] = pack2(Wx_in[(2 * q) * GG + col], Wx_in[(2 * q + 1) * GG + col]);
#pragma unroll
    for (int q = 0; q < HH / 2; ++q)
        whi[q] = pack2(Wh_in[(2 * q) * GG + col], Wh_in[(2 * q + 1) * GG + col]);

    const float bo = b_out[col];
    const float bi = b_in[col];
    // branch-free activation: g<3 -> sigm(x); g==3 -> tanh(x)=2*sigm(2x)-1
    const float kk = (g == 3) ? 2.0f : 1.0f;
    const float aa = (g == 3) ? 2.0f : 1.0f;
    const float cc = (g == 3) ? -1.0f : 0.0f;

    const int   pn = j >> 3;
    const int   ps = j & 7;
    const float bl = b_lin[pn];

    // W_lin -> LDS fp16 (1024 chunks, 2 per thread)
#pragma unroll
    for (int r = 0; r < 2; ++r) {
        const int mm = r * 512 + j;
        const int c = mm >> 6, n = mm & 63;
        F4H u;
#pragma unroll
        for (int q = 0; q < 4; ++q)
            u.h[q] = pack2(W_lin[n * HH + 8 * c + 2 * q],
                           W_lin[n * HH + 8 * c + 2 * q + 1]);
        wlf[c * 66 + n] = u.f4;
    }

    if (j < HH) { hb[j] = (_Float16)0.f; xib[j] = (_Float16)0.f; hib[j] = (_Float16)0.f; }
    float c_reg = 0.f, cn_reg = 0.f;   // redundant in all 4 quad lanes
    float o_all = 0.f;                 // outer o, broadcast each step
    __syncthreads();

    const _Float16* xpr = xp + (size_t)b * SS * GG + col;
    float* orow = out + (size_t)b * SS * OO;
    const float4* hb4 = (const float4*)hb;   // 16 chunks
    const float4* xi4 = (const float4*)xib;  // 16 chunks
    const float4* hi4 = (const float4*)hib;  // 16 chunks

    _Float16 xpc = xpr[0];

#pragma unroll 1
    for (int t = 0; t < SS; ++t) {
        // ---- phase A: outer gate for col = XP + h@Wh_out + b ----
        float a0 = bo + (float)xpc, a1 = 0.f, a2 = 0.f, a3 = 0.f;
#pragma unroll
        for (int c = 0; c < 16; ++c) {
            F4H hu; hu.f4 = hb4[c];
            a0 = dot2(who[4 * c + 0], hu.h[0], a0);
            a1 = dot2(who[4 * c + 1], hu.h[1], a1);
            a2 = dot2(who[4 * c + 2], hu.h[2], a2);
            a3 = dot2(who[4 * c + 3], hu.h[3], a3);
        }
        // prefetch next step's XP (independent; lands during phase C)
        const _Float16 xpn = xpr[(size_t)((t + 1) & (SS - 1)) * GG];
        const float accA = (a0 + a1) + (a2 + a3);
        const float v = fmaf(aa, sigm(kk * accA), cc);   // i/f/o/g by lane
        // quad tail (DPP): x_in = i*g at lane0, h_in = f*c at lane1
        const float vg3 = qdpp<QP_XOR3>(v);   // lane0 <- g-value
        o_all = qdpp<QP_BC2>(v);              // everyone keeps outer o
        if (g == 0)      xib[m] = (_Float16)(v * vg3);
        else if (g == 1) hib[m] = (_Float16)(v * c_reg);  // c_reg redundant-valid
        __syncthreads();   // S1

        // ---- phase C: inner gate for col ----
        float c0 = bi, c1 = 0.f, c2 = 0.f, c3 = 0.f;
#pragma unroll
        for (int c = 0; c < 16; ++c) {
            F4H xu; xu.f4 = xi4[c];
            c0 = dot2(wxi[4 * c + 0], xu.h[0], c0);
            c1 = dot2(wxi[4 * c + 1], xu.h[1], c1);
            c2 = dot2(wxi[4 * c + 2], xu.h[2], c2);
            c3 = dot2(wxi[4 * c + 3], xu.h[3], c3);
        }
#pragma unroll
        for (int c = 0; c < 16; ++c) {
            F4H hu; hu.f4 = hi4[c];
            c0 = dot2(whi[4 * c + 0], hu.h[0], c0);
            c1 = dot2(whi[4 * c + 1], hu.h[1], c1);
            c2 = dot2(whi[4 * c + 2], hu.h[2], c2);
            c3 = dot2(whi[4 * c + 3], hu.h[3], c3);
        }
        const float accC = (c0 + c1) + (c2 + c3);
        const float u = fmaf(aa, sigm(kk * accC), cc);    // ii/fi/oi/gi by lane
        // quad tail (DPP, redundant update in all lanes; P/F/O independent):
        const float ug3 = qdpp<QP_XOR3>(u);
        const float p0  = u * ug3;                 // ii*gi valid at lanes 0,3
        const float P   = qdpp<QP_BC0>(p0);        // ii*gi everywhere
        const float F   = qdpp<QP_BC1>(u);         // fi everywhere
        const float O   = qdpp<QP_BC2>(u);         // oi everywhere
        const float cn_new = fmaf(F, cn_reg, P);
        cn_reg = cn_new;
        const float c_new = O * tanh_c(cn_new);
        c_reg = c_new;
        const float h_new = o_all * tanh_c(c_new);
        if (g == 2) hb[m] = (_Float16)h_new;
        xpc = xpn;
        __syncthreads();   // S2

        // ---- phase E: fused projection (post-S2 — the ONLY placement that
        //      works, measured R8/R11/R13; store retires under next A+C) ----
        float p = 0.f;
#pragma unroll
        for (int q = 0; q < 2; ++q) {
            const int c = 2 * ps + q;
            F4H hu; hu.f4 = hb4[c];
            F4H wu; wu.f4 = wlf[c * 66 + pn];
            p = dot2(wu.h[0], hu.h[0], p);
            p = dot2(wu.h[1], hu.h[1], p);
            p = dot2(wu.h[2], hu.h[2], p);
            p = dot2(wu.h[3], hu.h[3], p);
        }
        p += __shfl_down(p, 4, 8);
        p += __shfl_down(p, 2, 8);
        p += __shfl_down(p, 1, 8);
        if (ps == 0) orow[t * OO + pn] = p + bl;
    }
}

// ============================================================================
// FALLBACK: exact R1 kernel (measured 4364 us) for when ws is too small.
// ============================================================================
__global__ void
__attribute__((amdgpu_flat_work_group_size(512, 512)))
__attribute__((amdgpu_waves_per_eu(2, 2)))
nlstm_scan(
    const float* __restrict__ x,
    const float* __restrict__ Wx_out, const float* __restrict__ Wh_out,
    const float* __restrict__ b_out,
    const float* __restrict__ Wx_in, const float* __restrict__ Wh_in,
    const float* __restrict__ b_in,
    const float* __restrict__ W_lin, const float* __restrict__ b_lin,
    float* __restrict__ out)
{
    const int b = blockIdx.x;
    const int j = threadIdx.x;

    __shared__ __align__(16) float4 wxf[8 * 512];
    __shared__ __align__(16) float4 wlf[16 * 66];
    __shared__ float xt[2][II][TT + 1];
    __shared__ __align__(16) f16x2 xb[2][II / 2];
    __shared__ __align__(16) f16x2 hb[HH / 2];
    __shared__ __align__(16) f16x2 xib[HH / 2];
    __shared__ __align__(16) f16x2 hib[HH / 2];
    __shared__ float cb[HH];
    __shared__ float cnb[HH];
    __shared__ float actO[GG];
    __shared__ float actI[GG];

    f16x2 who[HH / 2], wxi[HH / 2], whi[HH / 2];
#pragma unroll
    for (int m = 0; m < HH / 2; ++m)
        who[m] = pack2(Wh_out[(2 * m) * GG + j], Wh_out[(2 * m + 1) * GG + j]);
#pragma unroll
    for (int m = 0; m < HH / 2; ++m)
        wxi[m] = pack2(Wx_in[(2 * m) * GG + j], Wx_in[(2 * m + 1) * GG + j]);
#pragma unroll
    for (int m = 0; m < HH / 2; ++m)
        whi[m] = pack2(Wh_in[(2 * m) * GG + j], Wh_in[(2 * m + 1) * GG + j]);

    const float bo = b_out[j];
    const float bi = b_in[j];
    const int   pn = j >> 3;
    const int   ps = j & 7;
    const float bl = b_lin[pn];

#pragma unroll
    for (int c = 0; c < 8; ++c) {
        F4H u;
#pragma unroll
        for (int q = 0; q < 4; ++q)
            u.h[q] = pack2(Wx_out[(8 * c + 2 * q) * GG + j],
                           Wx_out[(8 * c + 2 * q + 1) * GG + j]);
        wxf[c * 512 + j] = u.f4;
    }
#pragma unroll
    for (int r = 0; r < 2; ++r) {
        const int m = r * 512 + j;
        const int c = m >> 6, n = m & 63;
        F4H u;
#pragma unroll
        for (int q = 0; q < 4; ++q)
            u.h[q] = pack2(W_lin[n * HH + 8 * c + 2 * q],
                           W_lin[n * HH + 8 * c + 2 * q + 1]);
        wlf[c * 66 + n] = u.f4;
    }

    const float* xrow = x + (size_t)b * II * SS;
    float* orow = out + (size_t)b * SS * OO;

    {
        const int row = j >> 3, tc = j & 7;
        const float4 v = *(const float4*)(xrow + (size_t)row * SS + 4 * tc);
        float* dst = &xt[0][row][4 * tc];
        dst[0] = v.x; dst[1] = v.y; dst[2] = v.z; dst[3] = v.w;
    }
    if (j < HH / 2) hb[j] = pack2(0.f, 0.f);
    if (j < HH) { cb[j] = 0.f; cnb[j] = 0.f; }
    if (j >= 256 && j < 256 + 32) {
        const int m = j - 256;
        xb[0][m] = pack2(xrow[(2 * m) * SS], xrow[(2 * m + 1) * SS]);
    }
    __syncthreads();

    const float4* hb4 = (const float4*)hb;
    const float4* xi4 = (const float4*)xib;
    const float4* hi4 = (const float4*)hib;

#pragma unroll 1
    for (int t = 0; t < SS; ++t) {
        const float4* xcur = (const float4*)xb[t & 1];
        float a0 = bo, a1 = 0.f, a2 = 0.f, a3 = 0.f;
#pragma unroll
        for (int c = 0; c < 8; ++c) {
            F4H xu; xu.f4 = xcur[c];
            F4H wu; wu.f4 = wxf[c * 512 + j];
            a0 = dot2(wu.h[0], xu.h[0], a0);
            a1 = dot2(wu.h[1], xu.h[1], a1);
            a2 = dot2(wu.h[2], xu.h[2], a2);
            a3 = dot2(wu.h[3], xu.h[3], a3);
        }
#pragma unroll
        for (int c = 0; c < 16; ++c) {
            F4H hu; hu.f4 = hb4[c];
            a0 = dot2(who[4 * c + 0], hu.h[0], a0);
            a1 = dot2(who[4 * c + 1], hu.h[1], a1);
            a2 = dot2(who[4 * c + 2], hu.h[2], a2);
            a3 = dot2(who[4 * c + 3], hu.h[3], a3);
        }
        {
            const float acc = (a0 + a1) + (a2 + a3);
            actO[j] = (j < 384) ? sigm(acc) : tanh_f(acc);
        }
        __syncthreads();

        if (j < II) {
            xib[j] = pack2(actO[2 * j] * actO[384 + 2 * j],
                           actO[2 * j + 1] * actO[384 + 2 * j + 1]);
        } else if (j < II + HH / 2) {
            const int m = j - II;
            hib[m] = pack2(actO[HH + 2 * m] * cb[2 * m],
                           actO[HH + 2 * m + 1] * cb[2 * m + 1]);
        }
        __syncthreads();

        float c0 = bi, c1 = 0.f, c2 = 0.f, c3 = 0.f;
#pragma unroll
        for (int c = 0; c < 16; ++c) {
            F4H xu; xu.f4 = xi4[c];
            c0 = dot2(wxi[4 * c + 0], xu.h[0], c0);
            c1 = dot2(wxi[4 * c + 1], xu.h[1], c1);
            c2 = dot2(wxi[4 * c + 2], xu.h[2], c2);
            c3 = dot2(wxi[4 * c + 3], xu.h[3], c3);
        }
#pragma unroll
        for (int c = 0; c < 16; ++c) {
            F4H hu; hu.f4 = hi4[c];
            c0 = dot2(whi[4 * c + 0], hu.h[0], c0);
            c1 = dot2(whi[4 * c + 1], hu.h[1], c1);
            c2 = dot2(whi[4 * c + 2], hu.h[2], c2);
            c3 = dot2(whi[4 * c + 3], hu.h[3], c3);
        }
        {
            const float acc2 = (c0 + c1) + (c2 + c3);
            actI[j] = (j < 384) ? sigm(acc2) : tanh_f(acc2);
        }
        __syncthreads();

        const bool doTile = ((t & 31) == 30) && (t + 2 < SS);
        float4 xld; int Tn = 0;
        if (doTile) {
            Tn = (t + 2) >> 5;
            const int row = j >> 3, tc = j & 7;
            xld = *(const float4*)(xrow + (size_t)row * SS + TT * Tn + 4 * tc);
        }
        if (j < HH) {
            const float cn_new = actI[HH + j] * cnb[j] + actI[j] * actI[384 + j];
            const float c_new  = actI[2 * HH + j] * tanh_f(cn_new);
            const float h_new  = actO[2 * HH + j] * tanh_f(c_new);
            cnb[j] = cn_new;
            cb[j]  = c_new;
            ((_Float16*)hb)[j] = (_Float16)h_new;
        } else if (j < HH + 32) {
            const int m = j - HH;
            const int tn = t + 1;
            const int tbn = (tn >> 5) & 1, ttn = tn & 31;
            xb[tn & 1][m] = pack2(xt[tbn][2 * m][ttn],
                                  xt[tbn][2 * m + 1][ttn]);
        }
        if (doTile) {
            const int row = j >> 3, tc = j & 7;
            float* dst = &xt[Tn & 1][row][4 * tc];
            dst[0] = xld.x; dst[1] = xld.y; dst[2] = xld.z; dst[3] = xld.w;
        }
        __syncthreads();

        float p = 0.f;
#pragma unroll
        for (int q = 0; q < 2; ++q) {
            const int c = 2 * ps + q;
            F4H hu; hu.f4 = hb4[c];
            F4H wu; wu.f4 = wlf[c * 66 + pn];
            p = dot2(wu.h[0], hu.h[0], p);
            p = dot2(wu.h[1], hu.h[1], p);
            p = dot2(wu.h[2], hu.h[2], p);
            p = dot2(wu.h[3], hu.h[3], p);
        }
        p += __shfl_down(p, 4, 8);
        p += __shfl_down(p, 2, 8);
        p += __shfl_down(p, 1, 8);
        if (ps == 0) orow[t * OO + pn] = p + bl;
    }
}

extern "C" void kernel_launch(void* const* d_in, const int* in_sizes, int n_in,
                              void* d_out, int out_size, void* d_ws, size_t ws_size,
                              hipStream_t stream) {
    (void)in_sizes; (void)n_in; (void)out_size;
    const float* x      = (const float*)d_in[0];
    const float* Wx_out = (const float*)d_in[1];
    const float* Wh_out = (const float*)d_in[2];
    const float* b_out  = (const float*)d_in[3];
    const float* Wx_in  = (const float*)d_in[4];
    const float* Wh_in  = (const float*)d_in[5];
    const float* b_in   = (const float*)d_in[6];
    const float* W_lin  = (const float*)d_in[7];
    const float* b_lin  = (const float*)d_in[8];
    float* out = (float*)d_out;

    if (d_ws != nullptr && ws_size >= XPBYTES) {
        _Float16* xpw = (_Float16*)d_ws;
        xp_gemm<<<dim3(16, BB), dim3(512), 0, stream>>>(x, Wx_out, xpw);
        nlstm_scan_xp<<<dim3(BB), dim3(512), 0, stream>>>(
            xpw, Wh_out, b_out, Wx_in, Wh_in, b_in, W_lin, b_lin, out);
    } else {
        nlstm_scan<<<dim3(BB), dim3(512), 0, stream>>>(
            x, Wx_out, Wh_out, b_out, Wx_in, Wh_in, b_in, W_lin, b_lin, out);
    }
}

// Round 15
// 3523.291 us; speedup vs baseline: 2.6295x; 1.0024x over previous
//
#include <hip/hip_runtime.h>
#include <hip/hip_fp16.h>

#define BB 128
#define II 64
#define SS 2048
#define HH 128
#define GG 512   // 4*H
#define OO 64
#define TT 32    // x time-tile width (fallback kernel)
#define TCH 128  // precompute t-chunk
#define XPBYTES ((size_t)BB * SS * GG * 2)

typedef _Float16 f16x2 __attribute__((ext_vector_type(2)));
union F4H { float4 f4; f16x2 h[4]; };

__device__ __forceinline__ f16x2 pack2(float a, float b) {
    f16x2 r; r.x = (_Float16)a; r.y = (_Float16)b; return r;
}

__device__ __forceinline__ float dot2(f16x2 w, f16x2 v, float c) {
#if __has_builtin(__builtin_amdgcn_fdot2)
    return __builtin_amdgcn_fdot2(w, v, c, false);
#else
    return fmaf((float)w.x, (float)v.x, fmaf((float)w.y, (float)v.y, c));
#endif
}

__device__ __forceinline__ float sigm(float v) {
    return __builtin_amdgcn_rcpf(1.0f + __expf(-v));
}
// original tanh (fallback kernel keeps R1 bit-exact behavior)
__device__ __forceinline__ float tanh_f(float v) {
    float a = fabsf(v);
    float e = __expf(-2.0f * a);
    float r = (1.0f - e) * __builtin_amdgcn_rcpf(1.0f + e);
    return v < 0.0f ? -r : r;
}
// branch-free tanh = 2*sigm(2v)-1 (safe at +/-inf)
__device__ __forceinline__ float tanh_c(float v) {
    return fmaf(2.0f, __builtin_amdgcn_rcpf(1.0f + __expf(-2.0f * v)), -1.0f);
}

// quad-scope shuffle via DPP quad_perm (VALU pipe ~4cyc)
template <int CTRL>
__device__ __forceinline__ float qdpp(float x) {
    return __int_as_float(__builtin_amdgcn_update_dpp(
        0, __float_as_int(x), CTRL, 0xF, 0xF, true));
}
#define QP_XOR3 0x1B   // [3,2,1,0]
#define QP_BC0  0x00   // [0,0,0,0]
#define QP_BC1  0x55   // [1,1,1,1]
#define QP_BC2  0xAA   // [2,2,2,2]

// LDS-only barrier: s_waitcnt lgkmcnt(0) + raw s_barrier, WITHOUT the
// vmcnt(0) drain that __syncthreads() emits. In-flight global ops (the XP
// prefetch load, projection store) stay in flight across the barrier and
// retire under the next dot phase instead of stalling the serial chain.
// Safe here: the only cross-thread deps at these barriers are LDS writes
// (xib/hib at S1, hb at S2), fully fenced by lgkmcnt(0). m139-verified
// pattern; "memory" clobber keeps compiler LDS ops on the right side.
__device__ __forceinline__ void lds_barrier() {
    asm volatile("s_waitcnt lgkmcnt(0)" ::: "memory");
    __builtin_amdgcn_s_barrier();
}

// ============================================================================
// XP precompute: XP[b][t][j] = sum_i x[b,i,t] * Wx_out[i,j], stored f16.
// ============================================================================
__global__ void __launch_bounds__(512)
xp_gemm(const float* __restrict__ x, const float* __restrict__ Wx_out,
        _Float16* __restrict__ xp)
{
    const int tc = blockIdx.x;          // 0..15
    const int b  = blockIdx.y;          // 0..127
    const int j  = threadIdx.x;         // gate column 0..511
    const int t0 = tc * TCH;

    __shared__ __align__(16) f16x2 x2s[TCH][36];

    f16x2 w2[32];
#pragma unroll
    for (int c = 0; c < 32; ++c)
        w2[c] = pack2(Wx_out[(2 * c) * GG + j], Wx_out[(2 * c + 1) * GG + j]);

    const float* xrow = x + (size_t)b * II * SS;
    const int r = j >> 3;
#pragma unroll
    for (int rep = 0; rep < 4; ++rep) {
        const int u = (j & 7) + 8 * rep;
        const float4 v = *(const float4*)(xrow + (size_t)r * SS + t0 + 4 * u);
        const int c = r >> 1, half = r & 1;
        ((_Float16*)&x2s[4 * u + 0][c])[half] = (_Float16)v.x;
        ((_Float16*)&x2s[4 * u + 1][c])[half] = (_Float16)v.y;
        ((_Float16*)&x2s[4 * u + 2][c])[half] = (_Float16)v.z;
        ((_Float16*)&x2s[4 * u + 3][c])[half] = (_Float16)v.w;
    }
    __syncthreads();

    _Float16* xpo = xp + ((size_t)b * SS + t0) * GG + j;
#pragma unroll 4
    for (int tt = 0; tt < TCH; ++tt) {
        const float4* xr4 = (const float4*)&x2s[tt][0];
        float a0 = 0.f, a1 = 0.f;
#pragma unroll
        for (int q = 0; q < 8; ++q) {
            F4H u; u.f4 = xr4[q];
            a0 = dot2(w2[4 * q + 0], u.h[0], a0);
            a1 = dot2(w2[4 * q + 1], u.h[1], a1);
            a0 = dot2(w2[4 * q + 2], u.h[2], a0);
            a1 = dot2(w2[4 * q + 3], u.h[3], a1);
        }
        xpo[(size_t)tt * GG] = (_Float16)(a0 + a1);
    }
}

// ============================================================================
// Scan — R12 optimum (3520-3531 us) with ONE register-neutral change:
// in-loop __syncthreads() -> lds_barrier() (lgkmcnt-only, no vmcnt drain).
// Theory: __syncthreads' vmcnt(0) forces the XP prefetch (HBM, ~500+ cyc
// residual) and the projection store to complete AT S1/S2, putting their
// latency on the serial chain; neither is needed until much later (xpn at
// next A-head, store never re-read). lgkmcnt(0) alone fences the actual
// cross-thread deps (xib/hib at S1, hb at S2).
// DO-NOT-TOUCH notes (all measured):
//   * REGISTER CLIFF (R8,R11): extra values live across phase C spill ->
//     FETCH 173->800+ MB -> 6x regression.
//   * E PLACEMENT (R13): projection must stay post-S2 (+6600 cyc/step else).
//   * LDS-resident Wh_out slower (R10); MFMA restructure (R5), cross-block
//     split (R3), batch-pairing (R4) all worse.
// ============================================================================
__global__ void __launch_bounds__(512)
nlstm_scan_xp(
    const _Float16* __restrict__ xp,
    const float* __restrict__ Wh_out, const float* __restrict__ b_out,
    const float* __restrict__ Wx_in, const float* __restrict__ Wh_in,
    const float* __restrict__ b_in,
    const float* __restrict__ W_lin, const float* __restrict__ b_lin,
    float* __restrict__ out)
{
    const int b = blockIdx.x;
    const int j = threadIdx.x;
    const int g = j & 3;          // gate lane within quad: 0=i 1=f 2=o 3=g
    const int m = j >> 2;         // h-column 0..127
    const int col = g * 128 + m;  // gate column in canonical layout

    __shared__ __align__(16) float4 wlf[16 * 66];      // W_lin fp16, 16.5 KB
    __shared__ __align__(16) _Float16 hb[HH];          // h fp16
    __shared__ __align__(16) _Float16 xib[HH];         // x_in fp16
    __shared__ __align__(16) _Float16 hib[HH];         // h_in fp16

    // register-resident fp16 weights (column col) : 192 regs (overflow->AGPR,
    // measured free on gfx950 unified file — R10)
    f16x2 who[HH / 2], wxi[HH / 2], whi[HH / 2];
#pragma unroll
    for (int q = 0; q < HH / 2; ++q)
        who[q] = pack2(Wh_out[(2 * q) * GG + col], Wh_out[(2 * q + 1) * GG + col]);
#pragma unroll
    for (int q = 0; q < HH / 2; ++q)
        wxi[q] = pack2(Wx_in[(2 * q) * GG + col], Wx_in[(2 * q + 1) * GG + col]);
#pragma unroll
    for (int q = 0; q < HH / 2; ++q)
        whi[q] = pack2(Wh_in[(2 * q) * GG + col], Wh_in[(2 * q + 1) * GG + col]);

    const float bo = b_out[col];
    const float bi = b_in[col];
    // branch-free activation: g<3 -> sigm(x); g==3 -> tanh(x)=2*sigm(2x)-1
    const float kk = (g == 3) ? 2.0f : 1.0f;
    const float aa = (g == 3) ? 2.0f : 1.0f;
    const float cc = (g == 3) ? -1.0f : 0.0f;

    const int   pn = j >> 3;
    const int   ps = j & 7;
    const float bl = b_lin[pn];

    // W_lin -> LDS fp16 (1024 chunks, 2 per thread)
#pragma unroll
    for (int r = 0; r < 2; ++r) {
        const int mm = r * 512 + j;
        const int c = mm >> 6, n = mm & 63;
        F4H u;
#pragma unroll
        for (int q = 0; q < 4; ++q)
            u.h[q] = pack2(W_lin[n * HH + 8 * c + 2 * q],
                           W_lin[n * HH + 8 * c + 2 * q + 1]);
        wlf[c * 66 + n] = u.f4;
    }

    if (j < HH) { hb[j] = (_Float16)0.f; xib[j] = (_Float16)0.f; hib[j] = (_Float16)0.f; }
    float c_reg = 0.f, cn_reg = 0.f;   // redundant in all 4 quad lanes
    float o_all = 0.f;                 // outer o, broadcast each step
    __syncthreads();

    const _Float16* xpr = xp + (size_t)b * SS * GG + col;
    float* orow = out + (size_t)b * SS * OO;
    const float4* hb4 = (const float4*)hb;   // 16 chunks
    const float4* xi4 = (const float4*)xib;  // 16 chunks
    const float4* hi4 = (const float4*)hib;  // 16 chunks

    _Float16 xpc = xpr[0];

#pragma unroll 1
    for (int t = 0; t < SS; ++t) {
        // ---- phase A: outer gate for col = XP + h@Wh_out + b ----
        float a0 = bo + (float)xpc, a1 = 0.f, a2 = 0.f, a3 = 0.f;
#pragma unroll
        for (int c = 0; c < 16; ++c) {
            F4H hu; hu.f4 = hb4[c];
            a0 = dot2(who[4 * c + 0], hu.h[0], a0);
            a1 = dot2(who[4 * c + 1], hu.h[1], a1);
            a2 = dot2(who[4 * c + 2], hu.h[2], a2);
            a3 = dot2(who[4 * c + 3], hu.h[3], a3);
        }
        // prefetch next step's XP (stays in flight across S1 now)
        const _Float16 xpn = xpr[(size_t)((t + 1) & (SS - 1)) * GG];
        const float accA = (a0 + a1) + (a2 + a3);
        const float v = fmaf(aa, sigm(kk * accA), cc);   // i/f/o/g by lane
        // quad tail (DPP): x_in = i*g at lane0, h_in = f*c at lane1
        const float vg3 = qdpp<QP_XOR3>(v);   // lane0 <- g-value
        o_all = qdpp<QP_BC2>(v);              // everyone keeps outer o
        if (g == 0)      xib[m] = (_Float16)(v * vg3);
        else if (g == 1) hib[m] = (_Float16)(v * c_reg);  // c_reg redundant-valid
        lds_barrier();   // S1 (lgkmcnt-only)

        // ---- phase C: inner gate for col ----
        float c0 = bi, c1 = 0.f, c2 = 0.f, c3 = 0.f;
#pragma unroll
        for (int c = 0; c < 16; ++c) {
            F4H xu; xu.f4 = xi4[c];
            c0 = dot2(wxi[4 * c + 0], xu.h[0], c0);
            c1 = dot2(wxi[4 * c + 1], xu.h[1], c1);
            c2 = dot2(wxi[4 * c + 2], xu.h[2], c2);
            c3 = dot2(wxi[4 * c + 3], xu.h[3], c3);
        }
#pragma unroll
        for (int c = 0; c < 16; ++c) {
            F4H hu; hu.f4 = hi4[c];
            c0 = dot2(whi[4 * c + 0], hu.h[0], c0);
            c1 = dot2(whi[4 * c + 1], hu.h[1], c1);
            c2 = dot2(whi[4 * c + 2], hu.h[2], c2);
            c3 = dot2(whi[4 * c + 3], hu.h[3], c3);
        }
        const float accC = (c0 + c1) + (c2 + c3);
        const float u = fmaf(aa, sigm(kk * accC), cc);    // ii/fi/oi/gi by lane
        // quad tail (DPP, redundant update in all lanes; P/F/O independent):
        const float ug3 = qdpp<QP_XOR3>(u);
        const float p0  = u * ug3;                 // ii*gi valid at lanes 0,3
        const float P   = qdpp<QP_BC0>(p0);        // ii*gi everywhere
        const float F   = qdpp<QP_BC1>(u);         // fi everywhere
        const float O   = qdpp<QP_BC2>(u);         // oi everywhere
        const float cn_new = fmaf(F, cn_reg, P);
        cn_reg = cn_new;
        const float c_new = O * tanh_c(cn_new);
        c_reg = c_new;
        const float h_new = o_all * tanh_c(c_new);
        if (g == 2) hb[m] = (_Float16)h_new;
        xpc = xpn;
        lds_barrier();   // S2 (lgkmcnt-only)

        // ---- phase E: fused projection (post-S2 — the ONLY placement that
        //      works, measured R8/R11/R13; store retires under next A+C) ----
        float p = 0.f;
#pragma unroll
        for (int q = 0; q < 2; ++q) {
            const int c = 2 * ps + q;
            F4H hu; hu.f4 = hb4[c];
            F4H wu; wu.f4 = wlf[c * 66 + pn];
            p = dot2(wu.h[0], hu.h[0], p);
            p = dot2(wu.h[1], hu.h[1], p);
            p = dot2(wu.h[2], hu.h[2], p);
            p = dot2(wu.h[3], hu.h[3], p);
        }
        p += __shfl_down(p, 4, 8);
        p += __shfl_down(p, 2, 8);
        p += __shfl_down(p, 1, 8);
        if (ps == 0) orow[t * OO + pn] = p + bl;
    }
}

// ============================================================================
// FALLBACK: exact R1 kernel (measured 4364 us) for when ws is too small.
// ============================================================================
__global__ void
__attribute__((amdgpu_flat_work_group_size(512, 512)))
__attribute__((amdgpu_waves_per_eu(2, 2)))
nlstm_scan(
    const float* __restrict__ x,
    const float* __restrict__ Wx_out, const float* __restrict__ Wh_out,
    const float* __restrict__ b_out,
    const float* __restrict__ Wx_in, const float* __restrict__ Wh_in,
    const float* __restrict__ b_in,
    const float* __restrict__ W_lin, const float* __restrict__ b_lin,
    float* __restrict__ out)
{
    const int b = blockIdx.x;
    const int j = threadIdx.x;

    __shared__ __align__(16) float4 wxf[8 * 512];
    __shared__ __align__(16) float4 wlf[16 * 66];
    __shared__ float xt[2][II][TT + 1];
    __shared__ __align__(16) f16x2 xb[2][II / 2];
    __shared__ __align__(16) f16x2 hb[HH / 2];
    __shared__ __align__(16) f16x2 xib[HH / 2];
    __shared__ __align__(16) f16x2 hib[HH / 2];
    __shared__ float cb[HH];
    __shared__ float cnb[HH];
    __shared__ float actO[GG];
    __shared__ float actI[GG];

    f16x2 who[HH / 2], wxi[HH / 2], whi[HH / 2];
#pragma unroll
    for (int m = 0; m < HH / 2; ++m)
        who[m] = pack2(Wh_out[(2 * m) * GG + j], Wh_out[(2 * m + 1) * GG + j]);
#pragma unroll
    for (int m = 0; m < HH / 2; ++m)
        wxi[m] = pack2(Wx_in[(2 * m) * GG + j], Wx_in[(2 * m + 1) * GG + j]);
#pragma unroll
    for (int m = 0; m < HH / 2; ++m)
        whi[m] = pack2(Wh_in[(2 * m) * GG + j], Wh_in[(2 * m + 1) * GG + j]);

    const float bo = b_out[j];
    const float bi = b_in[j];
    const int   pn = j >> 3;
    const int   ps = j & 7;
    const float bl = b_lin[pn];

#pragma unroll
    for (int c = 0; c < 8; ++c) {
        F4H u;
#pragma unroll
        for (int q = 0; q < 4; ++q)
            u.h[q] = pack2(Wx_out[(8 * c + 2 * q) * GG + j],
                           Wx_out[(8 * c + 2 * q + 1) * GG + j]);
        wxf[c * 512 + j] = u.f4;
    }
#pragma unroll
    for (int r = 0; r < 2; ++r) {
        const int m = r * 512 + j;
        const int c = m >> 6, n = m & 63;
        F4H u;
#pragma unroll
        for (int q = 0; q < 4; ++q)
            u.h[q] = pack2(W_lin[n * HH + 8 * c + 2 * q],
                           W_lin[n * HH + 8 * c + 2 * q + 1]);
        wlf[c * 66 + n] = u.f4;
    }

    const float* xrow = x + (size_t)b * II * SS;
    float* orow = out + (size_t)b * SS * OO;

    {
        const int row = j >> 3, tc = j & 7;
        const float4 v = *(const float4*)(xrow + (size_t)row * SS + 4 * tc);
        float* dst = &xt[0][row][4 * tc];
        dst[0] = v.x; dst[1] = v.y; dst[2] = v.z; dst[3] = v.w;
    }
    if (j < HH / 2) hb[j] = pack2(0.f, 0.f);
    if (j < HH) { cb[j] = 0.f; cnb[j] = 0.f; }
    if (j >= 256 && j < 256 + 32) {
        const int m = j - 256;
        xb[0][m] = pack2(xrow[(2 * m) * SS], xrow[(2 * m + 1) * SS]);
    }
    __syncthreads();

    const float4* hb4 = (const float4*)hb;
    const float4* xi4 = (const float4*)xib;
    const float4* hi4 = (const float4*)hib;

#pragma unroll 1
    for (int t = 0; t < SS; ++t) {
        const float4* xcur = (const float4*)xb[t & 1];
        float a0 = bo, a1 = 0.f, a2 = 0.f, a3 = 0.f;
#pragma unroll
        for (int c = 0; c < 8; ++c) {
            F4H xu; xu.f4 = xcur[c];
            F4H wu; wu.f4 = wxf[c * 512 + j];
            a0 = dot2(wu.h[0], xu.h[0], a0);
            a1 = dot2(wu.h[1], xu.h[1], a1);
            a2 = dot2(wu.h[2], xu.h[2], a2);
            a3 = dot2(wu.h[3], xu.h[3], a3);
        }
#pragma unroll
        for (int c = 0; c < 16; ++c) {
            F4H hu; hu.f4 = hb4[c];
            a0 = dot2(who[4 * c + 0], hu.h[0], a0);
            a1 = dot2(who[4 * c + 1], hu.h[1], a1);
            a2 = dot2(who[4 * c + 2], hu.h[2], a2);
            a3 = dot2(who[4 * c + 3], hu.h[3], a3);
        }
        {
            const float acc = (a0 + a1) + (a2 + a3);
            actO[j] = (j < 384) ? sigm(acc) : tanh_f(acc);
        }
        __syncthreads();

        if (j < II) {
            xib[j] = pack2(actO[2 * j] * actO[384 + 2 * j],
                           actO[2 * j + 1] * actO[384 + 2 * j + 1]);
        } else if (j < II + HH / 2) {
            const int m = j - II;
            hib[m] = pack2(actO[HH + 2 * m] * cb[2 * m],
                           actO[HH + 2 * m + 1] * cb[2 * m + 1]);
        }
        __syncthreads();

        float c0 = bi, c1 = 0.f, c2 = 0.f, c3 = 0.f;
#pragma unroll
        for (int c = 0; c < 16; ++c) {
            F4H xu; xu.f4 = xi4[c];
            c0 = dot2(wxi[4 * c + 0], xu.h[0], c0);
            c1 = dot2(wxi[4 * c + 1], xu.h[1], c1);
            c2 = dot2(wxi[4 * c + 2], xu.h[2], c2);
            c3 = dot2(wxi[4 * c + 3], xu.h[3], c3);
        }
#pragma unroll
        for (int c = 0; c < 16; ++c) {
            F4H hu; hu.f4 = hi4[c];
            c0 = dot2(whi[4 * c + 0], hu.h[0], c0);
            c1 = dot2(whi[4 * c + 1], hu.h[1], c1);
            c2 = dot2(whi[4 * c + 2], hu.h[2], c2);
            c3 = dot2(whi[4 * c + 3], hu.h[3], c3);
        }
        {
            const float acc2 = (c0 + c1) + (c2 + c3);
            actI[j] = (j < 384) ? sigm(acc2) : tanh_f(acc2);
        }
        __syncthreads();

        const bool doTile = ((t & 31) == 30) && (t + 2 < SS);
        float4 xld; int Tn = 0;
        if (doTile) {
            Tn = (t + 2) >> 5;
            const int row = j >> 3, tc = j & 7;
            xld = *(const float4*)(xrow + (size_t)row * SS + TT * Tn + 4 * tc);
        }
        if (j < HH) {
            const float cn_new = actI[HH + j] * cnb[j] + actI[j] * actI[384 + j];
            const float c_new  = actI[2 * HH + j] * tanh_f(cn_new);
            const float h_new  = actO[2 * HH + j] * tanh_f(c_new);
            cnb[j] = cn_new;
            cb[j]  = c_new;
            ((_Float16*)hb)[j] = (_Float16)h_new;
        } else if (j < HH + 32) {
            const int m = j - HH;
            const int tn = t + 1;
            const int tbn = (tn >> 5) & 1, ttn = tn & 31;
            xb[tn & 1][m] = pack2(xt[tbn][2 * m][ttn],
                                  xt[tbn][2 * m + 1][ttn]);
        }
        if (doTile) {
            const int row = j >> 3, tc = j & 7;
            float* dst = &xt[Tn & 1][row][4 * tc];
            dst[0] = xld.x; dst[1] = xld.y; dst[2] = xld.z; dst[3] = xld.w;
        }
        __syncthreads();

        float p = 0.f;
#pragma unroll
        for (int q = 0; q < 2; ++q) {
            const int c = 2 * ps + q;
            F4H hu; hu.f4 = hb4[c];
            F4H wu; wu.f4 = wlf[c * 66 + pn];
            p = dot2(wu.h[0], hu.h[0], p);
            p = dot2(wu.h[1], hu.h[1], p);
            p = dot2(wu.h[2], hu.h[2], p);
            p = dot2(wu.h[3], hu.h[3], p);
        }
        p += __shfl_down(p, 4, 8);
        p += __shfl_down(p, 2, 8);
        p += __shfl_down(p, 1, 8);
        if (ps == 0) orow[t * OO + pn] = p + bl;
    }
}

extern "C" void kernel_launch(void* const* d_in, const int* in_sizes, int n_in,
                              void* d_out, int out_size, void* d_ws, size_t ws_size,
                              hipStream_t stream) {
    (void)in_sizes; (void)n_in; (void)out_size;
    const float* x      = (const float*)d_in[0];
    const float* Wx_out = (const float*)d_in[1];
    const float* Wh_out = (const float*)d_in[2];
    const float* b_out  = (const float*)d_in[3];
    const float* Wx_in  = (const float*)d_in[4];
    const float* Wh_in  = (const float*)d_in[5];
    const float* b_in   = (const float*)d_in[6];
    const float* W_lin  = (const float*)d_in[7];
    const float* b_lin  = (const float*)d_in[8];
    float* out = (float*)d_out;

    if (d_ws != nullptr && ws_size >= XPBYTES) {
        _Float16* xpw = (_Float16*)d_ws;
        xp_gemm<<<dim3(16, BB), dim3(512), 0, stream>>>(x, Wx_out, xpw);
        nlstm_scan_xp<<<dim3(BB), dim3(512), 0, stream>>>(
            xpw, Wh_out, b_out, Wx_in, Wh_in, b_in, W_lin, b_lin, out);
    } else {
        nlstm_scan<<<dim3(BB), dim3(512), 0, stream>>>(
            x, Wx_out, Wh_out, b_out, Wx_in, Wh_in, b_in, W_lin, b_lin, out);
    }
}